// Round 12
// baseline (55.029 us; speedup 1.0000x reference)
//
#include <hip/hip_runtime.h>

#define VOCABN 256
#define DN 512
#define DSN 2
#define KN 5
#define BN 8
#define LN 8192
#define WN 12                     // window positions per block (multiple of lcm(2,3,4)=12)
#define NW12 ((LN + WN - 1) / WN) // 683 windows per batch
#define LOUTN (LN / DSN)          // 4096
#define NROWS (KN * VOCABN)       // 1280 G rows
#define ROWB (DN * 2)             // 1024 bytes per bf16 G row
#define KPLANE (VOCABN * ROWB)    // 262144 bytes per k-plane
#define ZOFFB (NROWS * ROWB)      // invalid-tap base: rows 1280+q*256 are zero rows
#define SBIAS_IDX (NROWS + 4 * VOCABN + 1)  // 2305
#define ISP 8                     // split over i: 8 chunks of 64

// Workspace layout (BYTES) — derived, do not hand-edit numbers:
//   Gp : ISP * NROWS * DN * 4 = 8 * 1280 * 512 * 4 = 20,971,520
//   G  : 2305 rows * ROWB                          =  2,360,320
//   SW : 2306 * 4                                  =      9,224
#define GP_BYTES ((size_t)ISP * NROWS * DN * 4)
#define G_OFF GP_BYTES
#define SW_OFF (G_OFF + (size_t)2305 * ROWB)

typedef float nf2 __attribute__((ext_vector_type(2)));  // clang vector for nontemporal store

__device__ inline unsigned short f2bf(float f) {  // RNE f32->bf16
  unsigned int x = __float_as_uint(f);
  return (unsigned short)((x + 0x7FFFu + ((x >> 16) & 1u)) >> 16);
}

// ---------------- kernel 1: build GEMM partials (coalesced cw reads) ----------------
// Gp[isp][k*256+v][o] = sum_{i in [isp*64, isp*64+64)} emb[v][i] * cw[o][i][k]
// grid 512 = 8vt x 8ot x 8isp; 256 thr; per thread 2v x 4o x 5k = 40 accumulators.
// cw row (o, i0..i0+32, all k) = 160 contiguous floats = 40 aligned float4s -> coalesced,
// de-interleaved into LDS wt[k][i][o]. Two 32-i sub-stages per block.
__global__ __launch_bounds__(256) void gbuild_kernel(const float* __restrict__ emb,
                                                     const float* __restrict__ cw,
                                                     float* __restrict__ Gp) {
  const int bx = blockIdx.x;
  const int vt = bx & 7, ot = (bx >> 3) & 7, isp = bx >> 6;
  const int v0 = vt * 32, o0 = ot * 64;
  const int tid = threadIdx.x;
  const int ox = tid & 15, vx = tid >> 4;  // ox: 4 o-cols each; vx: 2 v-rows each

  __shared__ float se[32][36];           // [i_local][v_local]  (32 v + pad)
  __shared__ float wt[KN][32][68];       // [k][i_local][o_local] (64 o + pad)

  float acc[2][4][KN] = {};

  // staging maps
  const int ec = tid & 31, eg = tid >> 5;  // emb: i-col, v-row group (4 rows each)
  const int co = tid >> 2, cj = tid & 3;   // cw: o-row (64), float4 slot base

  for (int sub = 0; sub < 2; ++sub) {
    const int i0 = isp * 64 + sub * 32;
    __syncthreads();  // protect previous stage's LDS reads
    // emb -> se (coalesced): rows v0+q, cols i0+ec
#pragma unroll
    for (int p = 0; p < 4; ++p) {
      const int q = eg * 4 + p;
      se[ec][q] = emb[(size_t)(v0 + q) * DN + i0 + ec];
    }
    // cw -> wt: per o-row, 160 contiguous floats (i_local,k); e = f4*4+m, i=e/5, k=e%5
    const float* crow = cw + (size_t)(o0 + co) * (DN * KN) + (size_t)i0 * KN;
#pragma unroll
    for (int it = 0; it < 10; ++it) {
      const int f4 = cj + it * 4;  // 0..39
      const float4 w4 = *(const float4*)(crow + f4 * 4);
      const int e0 = f4 * 4;
      wt[(e0 + 0) % KN][(e0 + 0) / KN][co] = w4.x;
      wt[(e0 + 1) % KN][(e0 + 1) / KN][co] = w4.y;
      wt[(e0 + 2) % KN][(e0 + 2) / KN][co] = w4.z;
      wt[(e0 + 3) % KN][(e0 + 3) / KN][co] = w4.w;
    }
    __syncthreads();
    // compute: 32 i-steps x 40 FMA
#pragma unroll 4
    for (int i = 0; i < 32; ++i) {
      const float2 a = *(const float2*)&se[i][vx * 2];
#pragma unroll
      for (int k = 0; k < KN; ++k) {
        const float4 b = *(const float4*)&wt[k][i][ox * 4];
        acc[0][0][k] += a.x * b.x; acc[0][1][k] += a.x * b.y;
        acc[0][2][k] += a.x * b.z; acc[0][3][k] += a.x * b.w;
        acc[1][0][k] += a.y * b.x; acc[1][1][k] += a.y * b.y;
        acc[1][2][k] += a.y * b.z; acc[1][3][k] += a.y * b.w;
      }
    }
  }
  // write partials: row = k*256 + v, cols o0+ox*4..+3
#pragma unroll
  for (int vi = 0; vi < 2; ++vi)
#pragma unroll
    for (int k = 0; k < KN; ++k) {
      const int row = k * VOCABN + v0 + vx * 2 + vi;
      float4 f;
      f.x = acc[vi][0][k];
      f.y = acc[vi][1][k];
      f.z = acc[vi][2][k];
      f.w = acc[vi][3][k];
      *(float4*)(Gp + ((size_t)isp * NROWS + row) * DN + o0 + ox * 4) = f;
    }
}

// ---------------- kernel 2: merged reduce + score table (round-11, ISP=8) ----------------
// grid NROWS+6 x 256 thr.
//   r < NROWS      : sum ISP partials, write bf16 row, SW[r] = row . score_w
//   NROWS..NROWS+4 : zero G row (NROWS + (r-NROWS)*VOCABN) and its SW slot
//   NROWS+5        : sbias -> SW[SBIAS_IDX]
__global__ __launch_bounds__(256) void gswr_kernel(const float* __restrict__ Gp,
                                                   const float* __restrict__ conv_b,
                                                   const float* __restrict__ score_w,
                                                   unsigned int* __restrict__ G32,
                                                   float* __restrict__ SW) {
  const int r = blockIdx.x;
  const int tid = threadIdx.x;
  __shared__ float sred[4];
  if (r >= NROWS && r < NROWS + 5) {  // zero rows
    const int z = NROWS + (r - NROWS) * VOCABN;
    G32[(size_t)z * 256 + tid] = 0u;
    if (tid == 0) SW[z] = 0.f;
    return;
  }
  const float2 sw2 = *(const float2*)(score_w + tid * 2);
  float sdot;
  if (r == NROWS + 5) {  // sbias = conv_b . score_w
    const float2 cb2 = *(const float2*)(conv_b + tid * 2);
    sdot = cb2.x * sw2.x + cb2.y * sw2.y;
  } else {
    float x = 0.f, y = 0.f;
#pragma unroll
    for (int isp = 0; isp < ISP; ++isp) {
      const float2 p = *(const float2*)(Gp + ((size_t)isp * NROWS + r) * DN + tid * 2);
      x += p.x;
      y += p.y;
    }
    G32[(size_t)r * 256 + tid] = (unsigned)f2bf(x) | ((unsigned)f2bf(y) << 16);
    sdot = x * sw2.x + y * sw2.y;
  }
#pragma unroll
  for (int off = 32; off > 0; off >>= 1) sdot += __shfl_xor(sdot, off, 64);
  if ((tid & 63) == 0) sred[tid >> 6] = sdot;
  __syncthreads();
  if (tid == 0) {
    const float v = sred[0] + sred[1] + sred[2] + sred[3];
    if (r == NROWS + 5) SW[SBIAS_IDX] = v;
    else SW[r] = v;
  }
}

// ---------------- kernel 3: fused GBST main (round-11 verbatim) ----------------
__global__ __launch_bounds__(256, 5) void gbst_main_kernel(const int* __restrict__ ids,
                                                           const unsigned short* __restrict__ G,
                                                           const float* __restrict__ SW,
                                                           const float* __restrict__ conv_b,
                                                           float* __restrict__ out) {
  const int blk = blockIdx.x;
  const int b = blk / NW12;
  const int w = blk % NW12;
  const int l0 = w * WN;
  const int tid = threadIdx.x;

  __shared__ float t_s[WN];
  __shared__ float4 wm_s[WN];

  // P0: block-uniform tap byte-offsets (compiler emits s_load + scalar ALU)
  int joff[WN + 4];
#pragma unroll
  for (int j = 0; j < WN + 4; ++j) {
    const int p = l0 + j - 2;
    const bool v = ((unsigned)p < (unsigned)LN);
    const int a = v ? (b * LN + p) : 0;
    const int id = ids[a];
    joff[j] = v ? (id * ROWB) : ZOFFB;
  }

  // P1: gathers (uint = 2 bf16 channels); scalar base + tid voffset
  const char* Gc = (const char*)G;
  float2 y[WN];
#pragma unroll
  for (int s = 0; s < WN; ++s) {
    float ax = 0.f, ay = 0.f;
#pragma unroll
    for (int kk = 0; kk < KN; ++kk) {
      const unsigned g = ((const unsigned*)(Gc + (joff[s + kk] + kk * KPLANE)))[tid];
      ax += __uint_as_float(g << 16);
      ay += __uint_as_float(g & 0xFFFF0000u);
    }
    y[s].x = ax;
    y[s].y = ay;
  }
  const float2 bias = *(const float2*)(conv_b + tid * 2);
#pragma unroll
  for (int s = 0; s < WN; ++s) {
    const bool valid = (l0 + s) < LN;  // block-uniform
    y[s].x = valid ? y[s].x + bias.x : 0.f;
    y[s].y = valid ? y[s].y + bias.y : 0.f;
  }

  // P2 (wave 0 only): scalar-loaded scores, then softmax
  if (tid < 64) {
    const float sbias = SW[SBIAS_IDX];
    float t[WN];
#pragma unroll
    for (int s = 0; s < WN; ++s) {
      float tv = sbias;
#pragma unroll
      for (int kk = 0; kk < KN; ++kk) tv += SW[(joff[s + kk] >> 10) + kk * VOCABN];
      t[s] = (l0 + s < LN) ? tv : 0.f;
    }
    if (tid == 0) {
#pragma unroll
      for (int s = 0; s < WN; ++s) t_s[s] = t[s];  // compile-time indices only
    }
    if (tid < WN && l0 + tid < LN) {
      const int ll = tid;
      float s1 = t_s[ll];
      int j2 = ll & ~1;
      float s2 = 0.5f * (t_s[j2] + t_s[j2 + 1]);
      int j3 = (ll / 3) * 3;
      float s3 = (1.f / 3.f) * (t_s[j3] + t_s[j3 + 1] + t_s[j3 + 2]);
      int j4 = ll & ~3;
      float s4 = 0.25f * (t_s[j4] + t_s[j4 + 1] + t_s[j4 + 2] + t_s[j4 + 3]);
      float mx = fmaxf(fmaxf(s1, s2), fmaxf(s3, s4));
      float e1 = __expf(s1 - mx), e2 = __expf(s2 - mx);
      float e3 = __expf(s3 - mx), e4 = __expf(s4 - mx);
      float inv = 1.f / (e1 + e2 + e3 + e4);
      wm_s[ll] = make_float4(e1 * inv, e2 * inv, e3 * inv, e4 * inv);
    }
  }

  // P3: pool sums (before barrier — waves 1-3 overlap wave 0's softmax)
  float2 S2[6], S3[4], S4[3];
#pragma unroll
  for (int j = 0; j < 6; ++j) {
    S2[j].x = y[2 * j].x + y[2 * j + 1].x;
    S2[j].y = y[2 * j].y + y[2 * j + 1].y;
  }
#pragma unroll
  for (int j = 0; j < 4; ++j) {
    S3[j].x = y[3 * j].x + y[3 * j + 1].x + y[3 * j + 2].x;
    S3[j].y = y[3 * j].y + y[3 * j + 1].y + y[3 * j + 2].y;
  }
#pragma unroll
  for (int j = 0; j < 3; ++j) {
    S4[j].x = S2[2 * j].x + S2[2 * j + 1].x;
    S4[j].y = S2[2 * j].y + S2[2 * j + 1].y;
  }
  __syncthreads();

  // P4: latent mix + final /2 downsample, nontemporal clang-vector stores
#pragma unroll
  for (int jo = 0; jo < WN / 2; ++jo) {
    const int orow = (l0 >> 1) + jo;
    if (orow < LOUTN) {
      float ax = 0.f, ay = 0.f;
#pragma unroll
      for (int dl = 0; dl < 2; ++dl) {
        const int ll = 2 * jo + dl;
        const float4 wv = wm_s[ll];
        const float c2 = wv.y * 0.5f;
        const float c3 = wv.z * (1.f / 3.f);
        const float c4 = wv.w * 0.25f;
        ax += wv.x * y[ll].x + c2 * S2[jo].x + c3 * S3[ll / 3].x + c4 * S4[jo >> 1].x;
        ay += wv.x * y[ll].y + c2 * S2[jo].y + c3 * S3[ll / 3].y + c4 * S4[jo >> 1].y;
      }
      nf2 o2;
      o2.x = 0.5f * ax;
      o2.y = 0.5f * ay;
      __builtin_nontemporal_store(o2, (nf2*)(out + ((size_t)b * LOUTN + orow) * DN + tid * 2));
    }
  }
}

extern "C" void kernel_launch(void* const* d_in, const int* in_sizes, int n_in,
                              void* d_out, int out_size, void* d_ws, size_t ws_size,
                              hipStream_t stream) {
  const int* ids = (const int*)d_in[0];
  const float* emb = (const float*)d_in[1];
  const float* conv_w = (const float*)d_in[2];
  const float* conv_b = (const float*)d_in[3];
  const float* score_w = (const float*)d_in[4];
  float* out = (float*)d_out;

  char* ws = (char*)d_ws;
  float* Gp = (float*)ws;                               // 20,971,520 B
  unsigned short* G = (unsigned short*)(ws + G_OFF);    // 2,360,320 B @ 20,971,520
  float* SW = (float*)(ws + SW_OFF);                    // 9,224 B @ 23,331,840

  gbuild_kernel<<<dim3(512), dim3(256), 0, stream>>>(emb, conv_w, Gp);
  gswr_kernel<<<dim3(NROWS + 6), dim3(256), 0, stream>>>(Gp, conv_b, score_w,
                                                         (unsigned int*)G, SW);
  gbst_main_kernel<<<dim3(BN * NW12), dim3(256), 0, stream>>>(ids, G, SW, conv_b, out);
}

// Round 13
// 54.924 us; speedup vs baseline: 1.0019x; 1.0019x over previous
//
#include <hip/hip_runtime.h>

#define VOCABN 256
#define DN 512
#define DSN 2
#define KN 5
#define BN 8
#define LN 8192
#define WN 12                     // window positions per block (multiple of lcm(2,3,4)=12)
#define NW12 ((LN + WN - 1) / WN) // 683 windows per batch
#define LOUTN (LN / DSN)          // 4096
#define NROWS (KN * VOCABN)       // 1280 G rows
#define ROWB (DN * 2)             // 1024 bytes per bf16 G row
#define KPLANE (VOCABN * ROWB)    // 262144 bytes per k-plane
#define ZOFFB (NROWS * ROWB)      // invalid-tap base: rows 1280+q*256 are zero rows
#define SBIAS_IDX (NROWS + 4 * VOCABN + 1)  // 2305
#define ISP 4                     // split over i: 4 chunks of 128

// Workspace layout (BYTES) — derived:
//   Wt : KN*DN*DN*4        =  5,242,880   @ 0
//   Gp : ISP*NROWS*DN*4    = 10,485,760   @ 5,242,880
//   G  : 2305*ROWB         =  2,360,320   @ 15,728,640
//   SW : 2306*4            =      9,224   @ 18,088,960
#define WT_BYTES ((size_t)KN * DN * DN * 4)
#define GP_OFF WT_BYTES
#define GP_BYTES ((size_t)ISP * NROWS * DN * 4)
#define G_OFF (GP_OFF + GP_BYTES)
#define SW_OFF (G_OFF + (size_t)2305 * ROWB)

typedef float nf2 __attribute__((ext_vector_type(2)));  // clang vector for nontemporal store

__device__ inline unsigned short f2bf(float f) {  // RNE f32->bf16
  unsigned int x = __float_as_uint(f);
  return (unsigned short)((x + 0x7FFFu + ((x >> 16) & 1u)) >> 16);
}

// ---------------- kernel 0: coalesced repack conv_w [O][I][K] -> Wt [K][I][O] ----------
// (round-4 verified verbatim) block: o-tile 64 x i-chunk 32 (all K).
__global__ __launch_bounds__(256) void repack_kernel(const float* __restrict__ cw,
                                                     float* __restrict__ Wt) {
  __shared__ float t[64][161];  // [o][i_local*5+k]
  const int o0 = (blockIdx.x % 8) * 64;
  const int i0 = (blockIdx.x / 8) * 32;
  const int tid = threadIdx.x;
  for (int idx = tid; idx < 64 * 160; idx += 256) {
    int o = idx / 160, c = idx % 160;
    t[o][c] = cw[(size_t)(o0 + o) * (DN * KN) + i0 * KN + c];
  }
  __syncthreads();
  for (int widx = tid; widx < KN * 32 * 64; widx += 256) {
    int o = widx % 64;
    int ii = (widx / 64) % 32;
    int k = widx / 2048;
    Wt[((size_t)k * DN + i0 + ii) * DN + o0 + o] = t[o][ii * 5 + k];
  }
}

// ---------------- kernel 1: build GEMM partials (round-7 core, coalesced Wt stage) ------
// Gp[isp][k*256+v][o] = sum_{i in [isp*128, isp*128+128)} emb[v][i] * Wt[k][i][o]
// grid 640 = 4vt x 8ot x (5k x 4isp); 256 thr; 4v x 4o per thread; 4 stages of 32 i.
__global__ __launch_bounds__(256) void gbuild_kernel(const float* __restrict__ emb,
                                                     const float* __restrict__ Wt,
                                                     float* __restrict__ Gp) {
  const int bx = blockIdx.x;
  const int vt = bx & 3, ot = (bx >> 2) & 7;
  const int kq = bx >> 5;
  const int k = kq % 5, isp = kq / 5;
  const int v0 = vt * 64, o0 = ot * 64;
  const int tid = threadIdx.x;
  const int ox = tid & 15, vx = tid >> 4;
  const int c = tid & 31, rr = tid >> 5;   // emb stage: i-col 0..31, row-group 0..7
  const int oq = tid & 15, ir = tid >> 4;  // Wt stage: o-float4 col, i-row 0..15
  __shared__ float se[32][68];  // [i][v]
  __shared__ float wt[32][68];  // [i][o]
  float acc[4][4] = {};
  for (int ic = 0; ic < 4; ++ic) {
    const int i0 = isp * 128 + ic * 32;
    __syncthreads();  // protect previous iter's reads
#pragma unroll
    for (int p = 0; p < 8; ++p) {
      const int q = p * 8 + rr;
      se[c][q] = emb[(size_t)(v0 + q) * DN + i0 + c];  // coalesced rows
    }
#pragma unroll
    for (int p = 0; p < 2; ++p) {
      const int i = p * 16 + ir;
      *(float4*)&wt[i][oq * 4] =
          *(const float4*)(Wt + ((size_t)k * DN + i0 + i) * DN + o0 + oq * 4);  // coalesced
    }
    __syncthreads();
#pragma unroll
    for (int i = 0; i < 32; ++i) {
      const float4 a = *(const float4*)&se[i][vx * 4];
      const float4 b = *(const float4*)&wt[i][ox * 4];
      acc[0][0] += a.x * b.x; acc[0][1] += a.x * b.y; acc[0][2] += a.x * b.z; acc[0][3] += a.x * b.w;
      acc[1][0] += a.y * b.x; acc[1][1] += a.y * b.y; acc[1][2] += a.y * b.z; acc[1][3] += a.y * b.w;
      acc[2][0] += a.z * b.x; acc[2][1] += a.z * b.y; acc[2][2] += a.z * b.z; acc[2][3] += a.z * b.w;
      acc[3][0] += a.w * b.x; acc[3][1] += a.w * b.y; acc[3][2] += a.w * b.z; acc[3][3] += a.w * b.w;
    }
  }
#pragma unroll
  for (int vi = 0; vi < 4; ++vi) {
    const int row = k * VOCABN + v0 + vx * 4 + vi;
    float4 f;
    f.x = acc[vi][0];
    f.y = acc[vi][1];
    f.z = acc[vi][2];
    f.w = acc[vi][3];
    *(float4*)(Gp + ((size_t)isp * NROWS + row) * DN + o0 + ox * 4) = f;
  }
}

// ---------------- kernel 2: merged reduce + score table (round-11 verbatim, ISP=4) ------
__global__ __launch_bounds__(256) void gswr_kernel(const float* __restrict__ Gp,
                                                   const float* __restrict__ conv_b,
                                                   const float* __restrict__ score_w,
                                                   unsigned int* __restrict__ G32,
                                                   float* __restrict__ SW) {
  const int r = blockIdx.x;
  const int tid = threadIdx.x;
  __shared__ float sred[4];
  if (r >= NROWS && r < NROWS + 5) {  // zero rows
    const int z = NROWS + (r - NROWS) * VOCABN;
    G32[(size_t)z * 256 + tid] = 0u;
    if (tid == 0) SW[z] = 0.f;
    return;
  }
  const float2 sw2 = *(const float2*)(score_w + tid * 2);
  float sdot;
  if (r == NROWS + 5) {  // sbias = conv_b . score_w
    const float2 cb2 = *(const float2*)(conv_b + tid * 2);
    sdot = cb2.x * sw2.x + cb2.y * sw2.y;
  } else {
    float x = 0.f, y = 0.f;
#pragma unroll
    for (int isp = 0; isp < ISP; ++isp) {
      const float2 p = *(const float2*)(Gp + ((size_t)isp * NROWS + r) * DN + tid * 2);
      x += p.x;
      y += p.y;
    }
    G32[(size_t)r * 256 + tid] = (unsigned)f2bf(x) | ((unsigned)f2bf(y) << 16);
    sdot = x * sw2.x + y * sw2.y;
  }
#pragma unroll
  for (int off = 32; off > 0; off >>= 1) sdot += __shfl_xor(sdot, off, 64);
  if ((tid & 63) == 0) sred[tid >> 6] = sdot;
  __syncthreads();
  if (tid == 0) {
    const float v = sred[0] + sred[1] + sred[2] + sred[3];
    if (r == NROWS + 5) SW[SBIAS_IDX] = v;
    else SW[r] = v;
  }
}

// ---------------- kernel 3: fused GBST main (round-11 verbatim) ----------------
__global__ __launch_bounds__(256, 5) void gbst_main_kernel(const int* __restrict__ ids,
                                                           const unsigned short* __restrict__ G,
                                                           const float* __restrict__ SW,
                                                           const float* __restrict__ conv_b,
                                                           float* __restrict__ out) {
  const int blk = blockIdx.x;
  const int b = blk / NW12;
  const int w = blk % NW12;
  const int l0 = w * WN;
  const int tid = threadIdx.x;

  __shared__ float t_s[WN];
  __shared__ float4 wm_s[WN];

  // P0: block-uniform tap byte-offsets (compiler emits s_load + scalar ALU)
  int joff[WN + 4];
#pragma unroll
  for (int j = 0; j < WN + 4; ++j) {
    const int p = l0 + j - 2;
    const bool v = ((unsigned)p < (unsigned)LN);
    const int a = v ? (b * LN + p) : 0;
    const int id = ids[a];
    joff[j] = v ? (id * ROWB) : ZOFFB;
  }

  // P1: gathers (uint = 2 bf16 channels); scalar base + tid voffset
  const char* Gc = (const char*)G;
  float2 y[WN];
#pragma unroll
  for (int s = 0; s < WN; ++s) {
    float ax = 0.f, ay = 0.f;
#pragma unroll
    for (int kk = 0; kk < KN; ++kk) {
      const unsigned g = ((const unsigned*)(Gc + (joff[s + kk] + kk * KPLANE)))[tid];
      ax += __uint_as_float(g << 16);
      ay += __uint_as_float(g & 0xFFFF0000u);
    }
    y[s].x = ax;
    y[s].y = ay;
  }
  const float2 bias = *(const float2*)(conv_b + tid * 2);
#pragma unroll
  for (int s = 0; s < WN; ++s) {
    const bool valid = (l0 + s) < LN;  // block-uniform
    y[s].x = valid ? y[s].x + bias.x : 0.f;
    y[s].y = valid ? y[s].y + bias.y : 0.f;
  }

  // P2 (wave 0 only): scalar-loaded scores, then softmax
  if (tid < 64) {
    const float sbias = SW[SBIAS_IDX];
    float t[WN];
#pragma unroll
    for (int s = 0; s < WN; ++s) {
      float tv = sbias;
#pragma unroll
      for (int kk = 0; kk < KN; ++kk) tv += SW[(joff[s + kk] >> 10) + kk * VOCABN];
      t[s] = (l0 + s < LN) ? tv : 0.f;
    }
    if (tid == 0) {
#pragma unroll
      for (int s = 0; s < WN; ++s) t_s[s] = t[s];  // compile-time indices only
    }
    if (tid < WN && l0 + tid < LN) {
      const int ll = tid;
      float s1 = t_s[ll];
      int j2 = ll & ~1;
      float s2 = 0.5f * (t_s[j2] + t_s[j2 + 1]);
      int j3 = (ll / 3) * 3;
      float s3 = (1.f / 3.f) * (t_s[j3] + t_s[j3 + 1] + t_s[j3 + 2]);
      int j4 = ll & ~3;
      float s4 = 0.25f * (t_s[j4] + t_s[j4 + 1] + t_s[j4 + 2] + t_s[j4 + 3]);
      float mx = fmaxf(fmaxf(s1, s2), fmaxf(s3, s4));
      float e1 = __expf(s1 - mx), e2 = __expf(s2 - mx);
      float e3 = __expf(s3 - mx), e4 = __expf(s4 - mx);
      float inv = 1.f / (e1 + e2 + e3 + e4);
      wm_s[ll] = make_float4(e1 * inv, e2 * inv, e3 * inv, e4 * inv);
    }
  }

  // P3: pool sums (before barrier — waves 1-3 overlap wave 0's softmax)
  float2 S2[6], S3[4], S4[3];
#pragma unroll
  for (int j = 0; j < 6; ++j) {
    S2[j].x = y[2 * j].x + y[2 * j + 1].x;
    S2[j].y = y[2 * j].y + y[2 * j + 1].y;
  }
#pragma unroll
  for (int j = 0; j < 4; ++j) {
    S3[j].x = y[3 * j].x + y[3 * j + 1].x + y[3 * j + 2].x;
    S3[j].y = y[3 * j].y + y[3 * j + 1].y + y[3 * j + 2].y;
  }
#pragma unroll
  for (int j = 0; j < 3; ++j) {
    S4[j].x = S2[2 * j].x + S2[2 * j + 1].x;
    S4[j].y = S2[2 * j].y + S2[2 * j + 1].y;
  }
  __syncthreads();

  // P4: latent mix + final /2 downsample, nontemporal clang-vector stores
#pragma unroll
  for (int jo = 0; jo < WN / 2; ++jo) {
    const int orow = (l0 >> 1) + jo;
    if (orow < LOUTN) {
      float ax = 0.f, ay = 0.f;
#pragma unroll
      for (int dl = 0; dl < 2; ++dl) {
        const int ll = 2 * jo + dl;
        const float4 wv = wm_s[ll];
        const float c2 = wv.y * 0.5f;
        const float c3 = wv.z * (1.f / 3.f);
        const float c4 = wv.w * 0.25f;
        ax += wv.x * y[ll].x + c2 * S2[jo].x + c3 * S3[ll / 3].x + c4 * S4[jo >> 1].x;
        ay += wv.x * y[ll].y + c2 * S2[jo].y + c3 * S3[ll / 3].y + c4 * S4[jo >> 1].y;
      }
      nf2 o2;
      o2.x = 0.5f * ax;
      o2.y = 0.5f * ay;
      __builtin_nontemporal_store(o2, (nf2*)(out + ((size_t)b * LOUTN + orow) * DN + tid * 2));
    }
  }
}

extern "C" void kernel_launch(void* const* d_in, const int* in_sizes, int n_in,
                              void* d_out, int out_size, void* d_ws, size_t ws_size,
                              hipStream_t stream) {
  const int* ids = (const int*)d_in[0];
  const float* emb = (const float*)d_in[1];
  const float* conv_w = (const float*)d_in[2];
  const float* conv_b = (const float*)d_in[3];
  const float* score_w = (const float*)d_in[4];
  float* out = (float*)d_out;

  char* ws = (char*)d_ws;
  float* Wt = (float*)ws;                               // 5,242,880 B @ 0
  float* Gp = (float*)(ws + GP_OFF);                    // 10,485,760 B @ 5,242,880
  unsigned short* G = (unsigned short*)(ws + G_OFF);    // 2,360,320 B @ 15,728,640
  float* SW = (float*)(ws + SW_OFF);                    // 9,224 B @ 18,088,960

  repack_kernel<<<dim3(128), dim3(256), 0, stream>>>(conv_w, Wt);
  gbuild_kernel<<<dim3(640), dim3(256), 0, stream>>>(emb, Wt, Gp);
  gswr_kernel<<<dim3(NROWS + 6), dim3(256), 0, stream>>>(Gp, conv_b, score_w,
                                                         (unsigned int*)G, SW);
  gbst_main_kernel<<<dim3(BN * NW12), dim3(256), 0, stream>>>(ids, G, SW, conv_b, out);
}